// Round 13
// baseline (195.346 us; speedup 1.0000x reference)
//
#include <hip/hip_runtime.h>

#define WINDOW   512
#define STEPSZ   256
#define NFRAMES  127
#define NSAMP    32768
#define NBATCH   512
#define NFREQ    256
#define BM       64
#define SAMP_TILE 16640          // 65 * 256 samples per tile
#define NPS      65

typedef __attribute__((ext_vector_type(8)))  short short8;   // 8 x bf16
typedef __attribute__((ext_vector_type(16))) float f32x16;   // 32x32 MFMA acc
typedef __attribute__((ext_vector_type(4)))  float f4;

// Verified pattern (G4): spread row-bits (byte bits 9-11) into 16B-slot bits.
#define SWZ(byt) ((byt) ^ ((((byt) >> 9) & 7) << 4))

static __device__ __forceinline__ short f2bf(float x) {
    union { float f; unsigned u; } v; v.f = x;
    unsigned r = (v.u + 0x7fffu + ((v.u >> 16) & 1u)) >> 16;
    return (short)r;
}

// ---- kernel 1: normalize basis -> bf16 32x32-fragment-major layout --------
// Bf[(ns*32 + ks)*64 + (n&31) + 32*kg2][8] holds B[n][k = ks*16 + kg2*8 + j]
// (real n -> ns 0..7, imag -> ns 8..15). Proven since R10.
__global__ __launch_bounds__(256) void prep_kernel(const float* __restrict__ br,
                                                   const float* __restrict__ bi,
                                                   short* __restrict__ Bf) {
    const int lane = threadIdx.x & 63;
    const int wid  = threadIdx.x >> 6;
    const int n    = blockIdx.x * 4 + wid;          // freq 0..255
    const float* pr = br + (size_t)n * WINDOW + lane * 8;
    const float* pi = bi + (size_t)n * WINDOW + lane * 8;
    f4 r0 = *(const f4*)pr;
    f4 r1 = *(const f4*)(pr + 4);
    f4 i0 = *(const f4*)pi;
    f4 i1 = *(const f4*)(pi + 4);
    float ss = 0.f;
#pragma unroll
    for (int j = 0; j < 4; ++j)
        ss += r0[j]*r0[j] + r1[j]*r1[j] + i0[j]*i0[j] + i1[j]*i1[j];
#pragma unroll
    for (int d = 1; d < 64; d <<= 1) ss += __shfl_xor(ss, d, 64);
    const float inv = 1.0f / (sqrtf(ss) + 1e-8f);
    short8 hr, hi;
#pragma unroll
    for (int j = 0; j < 4; ++j) {
        hr[j]     = f2bf(r0[j] * inv);
        hr[j + 4] = f2bf(r1[j] * inv);
        hi[j]     = f2bf(i0[j] * inv);
        hi[j + 4] = f2bf(i1[j] * inv);
    }
    const int ks  = lane >> 1, kg2 = lane & 1;
    const int nsR = n >> 5;
    const int nsI = 8 + (n >> 5);
    const int sl  = (n & 31) + 32 * kg2;
    *(short8*)(Bf + ((size_t)(nsR * 32 + ks) * 64 + sl) * 8) = hr;
    *(short8*)(Bf + ((size_t)(nsI * 32 + ks) * 64 + sl) * 8) = hi;
}

// ---- kernel 2: fused norms + bf16 32x32x16 MFMA GEMM -----------------------
// grid = 512 b * 2 m-halves = 1024 blocks; 256 thr (4 waves).
// Block = 64 frames x 512 cols; wave loops over 2 n-pairs with acc[2][2]
// reused (124 unified regs) -> 4 blocks/CU co-resident (LDS 134 KB,
// 16 waves/CU). n-iter 0's stores have NO barrier before n-iter 1's K-loop:
// write bursts overlap MFMA within and across the 4 staggered blocks.
__global__ __launch_bounds__(256, 4) void mel_kernel(const float* __restrict__ audio,
                                                     const short* __restrict__ Bf,
                                                     float* __restrict__ out) {
    __shared__ short smp[SAMP_TILE];   // 33280 B, swizzled bf16 samples
    __shared__ float ps[NPS];
    __shared__ float invn[BM];

    const int tid  = threadIdx.x;
    const int lane = tid & 63;
    const int wid  = tid >> 6;          // 0..3

    const int b  = blockIdx.x >> 1;
    const int mh = blockIdx.x & 1;
    const int f0 = mh * BM;

    float* out_norms = out;
    float* out_real  = out + 65024;
    float* out_imag  = out + 65024 + 16646144;

    const float* abase = audio + (size_t)b * NSAMP + f0 * STEPSZ;
    const int smax = NSAMP - f0 * STEPSZ - 8;

    const int rl32 = lane & 31;
    const int kg2  = lane >> 5;

    // ---- Phase 1: stream 8 samples/thread: f32 -> ss partial + bf16 LDS ----
#pragma unroll
    for (int it = 0; it < 9; ++it) {
        const int sl = it * 2048 + tid * 8;
        float ss = 0.f;
        if (sl < SAMP_TILE) {
            const int slc = sl < smax ? sl : smax;
            f4 v0 = *(const f4*)(abase + slc);
            f4 v1 = *(const f4*)(abase + slc + 4);
            short8 h;
#pragma unroll
            for (int q = 0; q < 4; ++q) {
                ss += v0[q]*v0[q] + v1[q]*v1[q];
                h[q]     = f2bf(v0[q]);
                h[q + 4] = f2bf(v1[q]);
            }
            const int byt = sl * 2;
            *(short8*)((char*)smp + SWZ(byt)) = h;
        }
        ss += __shfl_xor(ss, 1, 64);
        ss += __shfl_xor(ss, 2, 64);
        ss += __shfl_xor(ss, 4, 64);
        ss += __shfl_xor(ss, 8, 64);
        ss += __shfl_xor(ss, 16, 64);
        const int chunk = (it * 2048 + tid * 8) >> 8;
        if ((tid & 31) == 0 && chunk < NPS) ps[chunk] = ss;
    }
    __syncthreads();

    // ---- norms: frame f covers chunks f, f+1 ----
    if (tid < BM) {
        const float nrm = sqrtf(ps[tid] + ps[tid + 1]);
        const int fr = f0 + tid;
        if (fr < NFRAMES) out_norms[b * NFRAMES + fr] = nrm;
        invn[tid] = 1.0f / (nrm + 1e-8f);
    }
    __syncthreads();   // invn visible before epilogues

    // ---- Phase 2: per wave, 2 serial n-iterations of {K-loop, store} ----
    const int rb0 = (0 * 32 + rl32) * 512 + kg2 * 16;
    const int rb1 = (1 * 32 + rl32) * 512 + kg2 * 16;
    const int X0  = (rl32 & 7) << 4;
    const int X1  = ((rl32 + 1) & 7) << 4;
    const char* sb = (const char*)smp;

#pragma unroll
    for (int ni = 0; ni < 2; ++ni) {
        const int np = 4 * wid + 2 * ni;    // n-super pair {np, np+1}
        const short* bp0 = Bf + ((size_t)(np + 0) * 32 * 64 + lane) * 8;
        const short* bp1 = Bf + ((size_t)(np + 1) * 32 * 64 + lane) * 8;

        short8 bb[3][2];
#pragma unroll
        for (int d = 0; d < 3; ++d) {
            bb[d][0] = *(const short8*)(bp0 + (size_t)d * 512);
            bb[d][1] = *(const short8*)(bp1 + (size_t)d * 512);
        }

        f32x16 acc[2][2];
        acc[0][0] = (f32x16)0.f; acc[0][1] = (f32x16)0.f;
        acc[1][0] = (f32x16)0.f; acc[1][1] = (f32x16)0.f;

#pragma unroll
        for (int ks = 0; ks < 32; ++ks) {
            const int X  = (ks < 16) ? X0 : X1;
            const int kb = ks * 32;
            short8 a0 = *(const short8*)(sb + ((rb0 + kb) ^ X));
            short8 a1 = *(const short8*)(sb + ((rb1 + kb) ^ X));
            const int cur = ks % 3;
            short8 cb0 = bb[cur][0];
            short8 cb1 = bb[cur][1];
            if (ks < 29) {
                bb[cur][0] = *(const short8*)(bp0 + (size_t)(ks + 3) * 512);
                bb[cur][1] = *(const short8*)(bp1 + (size_t)(ks + 3) * 512);
            }
            acc[0][0] = __builtin_amdgcn_mfma_f32_32x32x16_bf16(a0, cb0, acc[0][0], 0, 0, 0);
            acc[1][0] = __builtin_amdgcn_mfma_f32_32x32x16_bf16(a1, cb0, acc[1][0], 0, 0, 0);
            acc[0][1] = __builtin_amdgcn_mfma_f32_32x32x16_bf16(a0, cb1, acc[0][1], 0, 0, 0);
            acc[1][1] = __builtin_amdgcn_mfma_f32_32x32x16_bf16(a1, cb1, acc[1][1], 0, 0, 0);
        }

        // store this 64x128 slab (no barrier: overlaps next n-iter's K-loop)
#pragma unroll
        for (int mi = 0; mi < 2; ++mi) {
#pragma unroll
            for (int s = 0; s < 2; ++s) {
                const int n = (np + s) * 32 + rl32;
                float* dst = (n < NFREQ) ? out_real : out_imag;
                const int kcol = n & (NFREQ - 1);
                const int rbase = mi * 32 + 4 * kg2;
#pragma unroll
                for (int r = 0; r < 16; ++r) {
                    const int rr = rbase + (r & 3) + 8 * (r >> 2);
                    const int fr = f0 + rr;
                    if (fr < NFRAMES)
                        dst[((size_t)b * NFRAMES + fr) * NFREQ + kcol] = acc[mi][s][r] * invn[rr];
                }
            }
        }
    }
}

extern "C" void kernel_launch(void* const* d_in, const int* in_sizes, int n_in,
                              void* d_out, int out_size, void* d_ws, size_t ws_size,
                              hipStream_t stream) {
    const float* audio = (const float*)d_in[0];
    const float* br    = (const float*)d_in[1];
    const float* bi    = (const float*)d_in[2];
    float* out = (float*)d_out;
    short* Bf  = (short*)d_ws;               // 512x512 bf16 = 512 KiB

    prep_kernel<<<64, 256, 0, stream>>>(br, bi, Bf);
    mel_kernel<<<NBATCH * 2, 256, 0, stream>>>(audio, Bf, out);
}

// Round 14
// 158.002 us; speedup vs baseline: 1.2363x; 1.2363x over previous
//
#include <hip/hip_runtime.h>

#define WINDOW   512
#define STEPSZ   256
#define NFRAMES  127
#define NSAMP    32768
#define NBATCH   512
#define NFREQ    256
#define BM       64
#define SAMP_TILE 16640          // 65 * 256 samples per half-batch tile
#define NPS      65

typedef __attribute__((ext_vector_type(8)))  short short8;   // 8 x bf16
typedef __attribute__((ext_vector_type(16))) float f32x16;   // 32x32 MFMA acc
typedef __attribute__((ext_vector_type(4)))  float f4;

// Verified pattern (G4): spread row-bits (byte bits 9-11) into 16B-slot bits.
#define SWZ(byt) ((byt) ^ ((((byt) >> 9) & 7) << 4))

static __device__ __forceinline__ short f2bf(float x) {
    union { float f; unsigned u; } v; v.f = x;
    unsigned r = (v.u + 0x7fffu + ((v.u >> 16) & 1u)) >> 16;
    return (short)r;
}

// ---- kernel 1: normalize basis -> bf16 32x32-fragment-major layout --------
// Bf[(ns*32 + ks)*64 + (n&31) + 32*kg2][8] holds B[n][k = ks*16 + kg2*8 + j]
// (real n -> ns 0..7, imag -> ns 8..15). Proven since R10.
__global__ __launch_bounds__(256) void prep_kernel(const float* __restrict__ br,
                                                   const float* __restrict__ bi,
                                                   short* __restrict__ Bf) {
    const int lane = threadIdx.x & 63;
    const int wid  = threadIdx.x >> 6;
    const int n    = blockIdx.x * 4 + wid;          // freq 0..255
    const float* pr = br + (size_t)n * WINDOW + lane * 8;
    const float* pi = bi + (size_t)n * WINDOW + lane * 8;
    f4 r0 = *(const f4*)pr;
    f4 r1 = *(const f4*)(pr + 4);
    f4 i0 = *(const f4*)pi;
    f4 i1 = *(const f4*)(pi + 4);
    float ss = 0.f;
#pragma unroll
    for (int j = 0; j < 4; ++j)
        ss += r0[j]*r0[j] + r1[j]*r1[j] + i0[j]*i0[j] + i1[j]*i1[j];
#pragma unroll
    for (int d = 1; d < 64; d <<= 1) ss += __shfl_xor(ss, d, 64);
    const float inv = 1.0f / (sqrtf(ss) + 1e-8f);
    short8 hr, hi;
#pragma unroll
    for (int j = 0; j < 4; ++j) {
        hr[j]     = f2bf(r0[j] * inv);
        hr[j + 4] = f2bf(r1[j] * inv);
        hi[j]     = f2bf(i0[j] * inv);
        hi[j + 4] = f2bf(i1[j] * inv);
    }
    const int ks  = lane >> 1, kg2 = lane & 1;
    const int nsR = n >> 5;
    const int nsI = 8 + (n >> 5);
    const int sl  = (n & 31) + 32 * kg2;
    *(short8*)(Bf + ((size_t)(nsR * 32 + ks) * 64 + sl) * 8) = hr;
    *(short8*)(Bf + ((size_t)(nsI * 32 + ks) * 64 + sl) * 8) = hi;
}

// Stage helpers: tile t+1 staged into smp[s1]/ps[s1] while K(t) computes.
// All-or-nothing per 32-lane group (sl spans 256 samples per group).
#define STAGE_ISSUE(IT)                                                   \
    if (!last) {                                                          \
        const int sl = (IT) * 4096 + tid * 8;                             \
        if (sl < SAMP_TILE) {                                             \
            const int slc = sl < smax_n ? sl : smax_n;                    \
            sv0 = *(const f4*)(abase_n + slc);                            \
            sv1 = *(const f4*)(abase_n + slc + 4);                        \
        }                                                                 \
    }

#define STAGE_USE(IT)                                                     \
    if (!last) {                                                          \
        const int sl = (IT) * 4096 + tid * 8;                             \
        float ss = 0.f;                                                   \
        if (sl < SAMP_TILE) {                                             \
            short8 h;                                                     \
            _Pragma("unroll")                                             \
            for (int q = 0; q < 4; ++q) {                                 \
                ss += sv0[q]*sv0[q] + sv1[q]*sv1[q];                      \
                h[q]     = f2bf(sv0[q]);                                  \
                h[q + 4] = f2bf(sv1[q]);                                  \
            }                                                             \
            *(short8*)((char*)smp[s1] + SWZ(sl * 2)) = h;                 \
        }                                                                 \
        ss += __shfl_xor(ss, 1, 64);                                      \
        ss += __shfl_xor(ss, 2, 64);                                      \
        ss += __shfl_xor(ss, 4, 64);                                      \
        ss += __shfl_xor(ss, 8, 64);                                      \
        ss += __shfl_xor(ss, 16, 64);                                     \
        const int chunk = ((IT) * 4096 + tid * 8) >> 8;                   \
        if ((tid & 31) == 0 && chunk < NPS) ps[s1][chunk] = ss;           \
    }

// ---- kernel 2: persistent 2-tile pipelined fused GEMM ----------------------
// grid = 512 blocks (2/CU); 512 thr (8 waves). Each block = one batch,
// tiles = its two 64-frame halves, LDS double-buffered. Stage(t+1) embedded
// in K(t) (issue/consume split); stores(t) overlap K(t+1). Per-wave K-loop
// and epilogue identical to R11 (proven addressing).
__global__ __launch_bounds__(512, 4) void mel_kernel(const float* __restrict__ audio,
                                                     const short* __restrict__ Bf,
                                                     float* __restrict__ out) {
    __shared__ short smp[2][SAMP_TILE];   // 2 x 33280 B, swizzled bf16
    __shared__ float ps[2][NPS];
    __shared__ float invn[2][BM];

    const int tid  = threadIdx.x;
    const int lane = tid & 63;
    const int wid  = tid >> 6;          // 0..7 (= wn)

    const int b = blockIdx.x;

    float* out_norms = out;
    float* out_real  = out + 65024;
    float* out_imag  = out + 65024 + 16646144;

    const int rl32 = lane & 31;
    const int kg2  = lane >> 5;
    const int wn   = wid;

    const short* bp0 = Bf + ((size_t)(2 * wn + 0) * 32 * 64 + lane) * 8;
    const short* bp1 = Bf + ((size_t)(2 * wn + 1) * 32 * 64 + lane) * 8;

    const int rb0 = (0 * 32 + rl32) * 512 + kg2 * 16;
    const int rb1 = (1 * 32 + rl32) * 512 + kg2 * 16;
    const int X0  = (rl32 & 7) << 4;
    const int X1  = ((rl32 + 1) & 7) << 4;

    // ---- prologue: stage tile 0 (mh=0) into buf 0 ----
    {
        const float* abase = audio + (size_t)b * NSAMP;
        const int smax = NSAMP - 8;     // mh=0 clamp (never hit below 16640)
#pragma unroll
        for (int it = 0; it < 5; ++it) {
            const int sl = it * 4096 + tid * 8;
            float ss = 0.f;
            if (sl < SAMP_TILE) {
                const int slc = sl < smax ? sl : smax;
                f4 v0 = *(const f4*)(abase + slc);
                f4 v1 = *(const f4*)(abase + slc + 4);
                short8 h;
#pragma unroll
                for (int q = 0; q < 4; ++q) {
                    ss += v0[q]*v0[q] + v1[q]*v1[q];
                    h[q]     = f2bf(v0[q]);
                    h[q + 4] = f2bf(v1[q]);
                }
                *(short8*)((char*)smp[0] + SWZ(sl * 2)) = h;
            }
            ss += __shfl_xor(ss, 1, 64);
            ss += __shfl_xor(ss, 2, 64);
            ss += __shfl_xor(ss, 4, 64);
            ss += __shfl_xor(ss, 8, 64);
            ss += __shfl_xor(ss, 16, 64);
            const int chunk = (it * 4096 + tid * 8) >> 8;
            if ((tid & 31) == 0 && chunk < NPS) ps[0][chunk] = ss;
        }
        __syncthreads();
        if (tid < BM) {      // norms tile 0 (frames 0..63)
            const float nrm = sqrtf(ps[0][tid] + ps[0][tid + 1]);
            out_norms[b * NFRAMES + tid] = nrm;
            invn[0][tid] = 1.0f / (nrm + 1e-8f);
        }
    }

    // ---- 2-tile pipeline ----
    for (int t = 0; t < 2; ++t) {
        const bool last = (t == 1);
        const int  s1   = (t + 1) & 1;
        const int  f0   = t * BM;
        // next tile (mh=1) staging geometry
        const float* abase_n = audio + (size_t)b * NSAMP + 16384;
        const int    smax_n  = NSAMP - 16384 - 8;

        const char* sb = (const char*)smp[t & 1];
        f4 sv0, sv1;

        // even/odd depth-2 B prefetch
        short8 eb0 = *(const short8*)bp0;
        short8 eb1 = *(const short8*)bp1;
        short8 ob0 = *(const short8*)(bp0 + 512);
        short8 ob1 = *(const short8*)(bp1 + 512);

        f32x16 acc[2][2];
        acc[0][0] = (f32x16)0.f; acc[0][1] = (f32x16)0.f;
        acc[1][0] = (f32x16)0.f; acc[1][1] = (f32x16)0.f;

#pragma unroll
        for (int ks = 0; ks < 32; ++ks) {
            const int X  = (ks < 16) ? X0 : X1;
            const int kb = ks * 32;
            short8 a0 = *(const short8*)(sb + ((rb0 + kb) ^ X));
            short8 a1 = *(const short8*)(sb + ((rb1 + kb) ^ X));

            if (ks == 0)  { STAGE_ISSUE(0) }
            if (ks == 4)  { STAGE_USE(0) }
            if (ks == 6)  { STAGE_ISSUE(1) }
            if (ks == 10) { STAGE_USE(1) }
            if (ks == 12) { STAGE_ISSUE(2) }
            if (ks == 16) { STAGE_USE(2) }
            if (ks == 18) { STAGE_ISSUE(3) }
            if (ks == 22) { STAGE_USE(3) }
            if (ks == 24) { STAGE_ISSUE(4) }
            if (ks == 28) { STAGE_USE(4) }

            short8 cb0, cb1;
            if ((ks & 1) == 0) {
                cb0 = eb0; cb1 = eb1;
                if (ks < 30) {
                    eb0 = *(const short8*)(bp0 + (size_t)(ks + 2) * 512);
                    eb1 = *(const short8*)(bp1 + (size_t)(ks + 2) * 512);
                }
            } else {
                cb0 = ob0; cb1 = ob1;
                if (ks < 30) {
                    ob0 = *(const short8*)(bp0 + (size_t)(ks + 2) * 512);
                    ob1 = *(const short8*)(bp1 + (size_t)(ks + 2) * 512);
                }
            }
            acc[0][0] = __builtin_amdgcn_mfma_f32_32x32x16_bf16(a0, cb0, acc[0][0], 0, 0, 0);
            acc[1][0] = __builtin_amdgcn_mfma_f32_32x32x16_bf16(a1, cb0, acc[1][0], 0, 0, 0);
            acc[0][1] = __builtin_amdgcn_mfma_f32_32x32x16_bf16(a0, cb1, acc[0][1], 0, 0, 0);
            acc[1][1] = __builtin_amdgcn_mfma_f32_32x32x16_bf16(a1, cb1, acc[1][1], 0, 0, 0);
        }

        __syncthreads();   // stage(t+1) LDS complete; K(t) reads done

        if (!last && tid < BM) {   // norms tile 1 (frames 64..126)
            const float nrm = sqrtf(ps[s1][tid] + ps[s1][tid + 1]);
            const int fr = BM + tid;
            if (fr < NFRAMES) out_norms[b * NFRAMES + fr] = nrm;
            invn[s1][tid] = 1.0f / (nrm + 1e-8f);
        }

        // ---- epilogue tile t (stores overlap next tile's K-loop) ----
#pragma unroll
        for (int mi = 0; mi < 2; ++mi) {
#pragma unroll
            for (int s = 0; s < 2; ++s) {
                const int n = (2 * wn + s) * 32 + rl32;
                float* dst = (n < NFREQ) ? out_real : out_imag;
                const int kcol = n & (NFREQ - 1);
                const int rbase = mi * 32 + 4 * kg2;
#pragma unroll
                for (int r = 0; r < 16; ++r) {
                    const int rr = rbase + (r & 3) + 8 * (r >> 2);
                    const int fr = f0 + rr;
                    if (fr < NFRAMES)
                        dst[((size_t)b * NFRAMES + fr) * NFREQ + kcol] = acc[mi][s][r] * invn[t & 1][rr];
                }
            }
        }
    }
}

extern "C" void kernel_launch(void* const* d_in, const int* in_sizes, int n_in,
                              void* d_out, int out_size, void* d_ws, size_t ws_size,
                              hipStream_t stream) {
    const float* audio = (const float*)d_in[0];
    const float* br    = (const float*)d_in[1];
    const float* bi    = (const float*)d_in[2];
    float* out = (float*)d_out;
    short* Bf  = (short*)d_ws;               // 512x512 bf16 = 512 KiB

    prep_kernel<<<64, 256, 0, stream>>>(br, bi, Bf);
    mel_kernel<<<NBATCH, 512, 0, stream>>>(audio, Bf, out);
}

// Round 15
// 73.818 us; speedup vs baseline: 2.6463x; 2.1404x over previous
//
#include <hip/hip_runtime.h>

#define WINDOW   512
#define STEPSZ   256
#define NFRAMES  127
#define NSAMP    32768
#define NBATCH   512
#define NFREQ    256
#define BM       64
#define SAMP_TILE 16640          // 65 * 256 samples per tile
#define NPS      65

typedef __attribute__((ext_vector_type(8)))  short short8;   // 8 x bf16
typedef __attribute__((ext_vector_type(16))) float f32x16;   // 32x32 MFMA acc
typedef __attribute__((ext_vector_type(4)))  float f4;

// Verified pattern (G4): spread row-bits (byte bits 9-11) into 16B-slot bits.
#define SWZ(byt) ((byt) ^ ((((byt) >> 9) & 7) << 4))

static __device__ __forceinline__ short f2bf(float x) {
    union { float f; unsigned u; } v; v.f = x;
    unsigned r = (v.u + 0x7fffu + ((v.u >> 16) & 1u)) >> 16;
    return (short)r;
}

// ---- kernel 1: normalize basis -> bf16 32x32-fragment-major layout --------
// Bf[(ns*32 + ks)*64 + (n&31) + 32*kg2][8] holds B[n][k = ks*16 + kg2*8 + j]
// (real n -> ns 0..7, imag -> ns 8..15). Proven since R10.
__global__ __launch_bounds__(256) void prep_kernel(const float* __restrict__ br,
                                                   const float* __restrict__ bi,
                                                   short* __restrict__ Bf) {
    const int lane = threadIdx.x & 63;
    const int wid  = threadIdx.x >> 6;
    const int n    = blockIdx.x * 4 + wid;          // freq 0..255
    const float* pr = br + (size_t)n * WINDOW + lane * 8;
    const float* pi = bi + (size_t)n * WINDOW + lane * 8;
    f4 r0 = *(const f4*)pr;
    f4 r1 = *(const f4*)(pr + 4);
    f4 i0 = *(const f4*)pi;
    f4 i1 = *(const f4*)(pi + 4);
    float ss = 0.f;
#pragma unroll
    for (int j = 0; j < 4; ++j)
        ss += r0[j]*r0[j] + r1[j]*r1[j] + i0[j]*i0[j] + i1[j]*i1[j];
#pragma unroll
    for (int d = 1; d < 64; d <<= 1) ss += __shfl_xor(ss, d, 64);
    const float inv = 1.0f / (sqrtf(ss) + 1e-8f);
    short8 hr, hi;
#pragma unroll
    for (int j = 0; j < 4; ++j) {
        hr[j]     = f2bf(r0[j] * inv);
        hr[j + 4] = f2bf(r1[j] * inv);
        hi[j]     = f2bf(i0[j] * inv);
        hi[j + 4] = f2bf(i1[j] * inv);
    }
    const int ks  = lane >> 1, kg2 = lane & 1;
    const int nsR = n >> 5;
    const int nsI = 8 + (n >> 5);
    const int sl  = (n & 31) + 32 * kg2;
    *(short8*)(Bf + ((size_t)(nsR * 32 + ks) * 64 + sl) * 8) = hr;
    *(short8*)(Bf + ((size_t)(nsI * 32 + ks) * 64 + sl) * 8) = hi;
}

// ---- kernel 2: norms only (streams audio -> L3, writes invn + norms) ------
// Proven in R12 (correct; not the bottleneck there).
__global__ __launch_bounds__(512) void norms_kernel(const float* __restrict__ audio,
                                                    float* __restrict__ invn_g,
                                                    float* __restrict__ out_norms) {
    __shared__ float ps[128];
    const int tid = threadIdx.x;
    const int b   = blockIdx.x;
    const float* src = audio + (size_t)b * NSAMP;
#pragma unroll
    for (int it = 0; it < 8; ++it) {
        const int s = it * 4096 + tid * 8;
        f4 v0 = *(const f4*)(src + s);
        f4 v1 = *(const f4*)(src + s + 4);
        float ss = 0.f;
#pragma unroll
        for (int q = 0; q < 4; ++q) ss += v0[q]*v0[q] + v1[q]*v1[q];
        ss += __shfl_xor(ss, 1, 64);
        ss += __shfl_xor(ss, 2, 64);
        ss += __shfl_xor(ss, 4, 64);
        ss += __shfl_xor(ss, 8, 64);
        ss += __shfl_xor(ss, 16, 64);
        if ((tid & 31) == 0) ps[s >> 8] = ss;   // 16 chunk-partials per iter
    }
    __syncthreads();
    if (tid < NFRAMES) {
        const float nrm = sqrtf(ps[tid] + ps[tid + 1]);   // frame = chunks f,f+1
        out_norms[b * NFRAMES + tid] = nrm;
        invn_g[b * 128 + tid] = 1.0f / (nrm + 1e-8f);
    } else if (tid == 127) {
        invn_g[b * 128 + 127] = 0.0f;                     // pad row
    }
}

// ---- kernel 3: bf16 32x32x16 MFMA GEMM (R11 body minus norm work) ----------
// grid = 512 b * 2 m-halves = 1024 blocks; 512 thr (8 waves, 1m x 8n).
// Phase 1 is a pure stream (load f32 -> cvt bf16 -> swizzled LDS): no shfl
// chains, no ps. invn read from global (L2-hot) via a 64-float LDS stage.
// K-loop/epilogue identical to R11. Audio is L3-hot after norms_kernel.
__global__ __launch_bounds__(512, 4) void gemm_kernel(const float* __restrict__ audio,
                                                      const short* __restrict__ Bf,
                                                      const float* __restrict__ invn_g,
                                                      float* __restrict__ out) {
    __shared__ short smp[SAMP_TILE];   // 33280 B, swizzled bf16 samples
    __shared__ float invn_s[BM];

    const int tid  = threadIdx.x;
    const int lane = tid & 63;
    const int wid  = tid >> 6;          // 0..7 (= wn)

    const int b  = blockIdx.x >> 1;
    const int mh = blockIdx.x & 1;
    const int f0 = mh * BM;

    float* out_real = out + 65024;
    float* out_imag = out + 65024 + 16646144;

    const float* abase = audio + (size_t)b * NSAMP + f0 * STEPSZ;
    const int smax = NSAMP - f0 * STEPSZ - 8;

    const int rl32 = lane & 31;
    const int kg2  = lane >> 5;
    const int wn   = wid;               // 8 waves, all distinct n

    const short* bp0 = Bf + ((size_t)(2 * wn + 0) * 32 * 64 + lane) * 8;
    const short* bp1 = Bf + ((size_t)(2 * wn + 1) * 32 * 64 + lane) * 8;

    // ---- depth-3 B prefetch (independent of LDS phase) ----
    short8 bb[3][2];
#pragma unroll
    for (int d = 0; d < 3; ++d) {
        bb[d][0] = *(const short8*)(bp0 + (size_t)d * 512);
        bb[d][1] = *(const short8*)(bp1 + (size_t)d * 512);
    }

    // ---- Phase 1: pure stream: f32 -> bf16 -> swizzled LDS (no reductions) ----
#pragma unroll
    for (int it = 0; it < 5; ++it) {
        const int sl = it * 4096 + tid * 8;
        if (sl < SAMP_TILE) {
            const int slc = sl < smax ? sl : smax;
            f4 v0 = *(const f4*)(abase + slc);
            f4 v1 = *(const f4*)(abase + slc + 4);
            short8 h;
#pragma unroll
            for (int q = 0; q < 4; ++q) {
                h[q]     = f2bf(v0[q]);
                h[q + 4] = f2bf(v1[q]);
            }
            *(short8*)((char*)smp + SWZ(sl * 2)) = h;
        }
    }
    if (tid < BM) invn_s[tid] = invn_g[b * 128 + f0 + tid];
    __syncthreads();

    // ---- Phase 2: K-loop (32 steps of k=16), 32x32x16 MFMA ----
    const int rb0 = (0 * 32 + rl32) * 512 + kg2 * 16;
    const int rb1 = (1 * 32 + rl32) * 512 + kg2 * 16;
    const int X0  = (rl32 & 7) << 4;
    const int X1  = ((rl32 + 1) & 7) << 4;
    const char* sb = (const char*)smp;

    f32x16 acc[2][2];
    acc[0][0] = (f32x16)0.f; acc[0][1] = (f32x16)0.f;
    acc[1][0] = (f32x16)0.f; acc[1][1] = (f32x16)0.f;

#pragma unroll
    for (int ks = 0; ks < 32; ++ks) {
        const int X  = (ks < 16) ? X0 : X1;
        const int kb = ks * 32;
        short8 a0 = *(const short8*)(sb + ((rb0 + kb) ^ X));
        short8 a1 = *(const short8*)(sb + ((rb1 + kb) ^ X));
        const int cur = ks % 3;
        short8 cb0 = bb[cur][0];
        short8 cb1 = bb[cur][1];
        if (ks < 29) {
            bb[cur][0] = *(const short8*)(bp0 + (size_t)(ks + 3) * 512);
            bb[cur][1] = *(const short8*)(bp1 + (size_t)(ks + 3) * 512);
        }
        acc[0][0] = __builtin_amdgcn_mfma_f32_32x32x16_bf16(a0, cb0, acc[0][0], 0, 0, 0);
        acc[1][0] = __builtin_amdgcn_mfma_f32_32x32x16_bf16(a1, cb0, acc[1][0], 0, 0, 0);
        acc[0][1] = __builtin_amdgcn_mfma_f32_32x32x16_bf16(a0, cb1, acc[0][1], 0, 0, 0);
        acc[1][1] = __builtin_amdgcn_mfma_f32_32x32x16_bf16(a1, cb1, acc[1][1], 0, 0, 0);
    }

    // ---- Epilogue: C/D map col=lane&31, row=(reg&3)+8*(reg>>2)+4*(lane>>5) ----
#pragma unroll
    for (int mi = 0; mi < 2; ++mi) {
#pragma unroll
        for (int s = 0; s < 2; ++s) {
            const int n = (2 * wn + s) * 32 + rl32;
            float* dst = (n < NFREQ) ? out_real : out_imag;
            const int kcol = n & (NFREQ - 1);
            const int rbase = mi * 32 + 4 * kg2;
#pragma unroll
            for (int r = 0; r < 16; ++r) {
                const int rr = rbase + (r & 3) + 8 * (r >> 2);
                const int fr = f0 + rr;
                if (fr < NFRAMES)
                    dst[((size_t)b * NFRAMES + fr) * NFREQ + kcol] = acc[mi][s][r] * invn_s[rr];
            }
        }
    }
}

extern "C" void kernel_launch(void* const* d_in, const int* in_sizes, int n_in,
                              void* d_out, int out_size, void* d_ws, size_t ws_size,
                              hipStream_t stream) {
    const float* audio = (const float*)d_in[0];
    const float* br    = (const float*)d_in[1];
    const float* bi    = (const float*)d_in[2];
    float* out = (float*)d_out;
    short* Bf     = (short*)d_ws;                          // 512 KiB
    float* invn_g = (float*)((char*)d_ws + (1 << 20));     // 256 KiB

    prep_kernel<<<64, 256, 0, stream>>>(br, bi, Bf);
    norms_kernel<<<NBATCH, 512, 0, stream>>>(audio, invn_g, out);
    gemm_kernel<<<NBATCH * 2, 512, 0, stream>>>(audio, Bf, invn_g, out);
}